// Round 1
// baseline (495.109 us; speedup 1.0000x reference)
//
#include <hip/hip_runtime.h>

// CRF Viterbi — R5: two-phase restructure.
// Phase 1 (serial, 1024 one-wave blocks): max-plus recurrence ONLY.
//   The argmax never feeds the recurrence, so it is evicted from the serial
//   loop. S(t) rows are stored IN-PLACE into the backpointer output slots
//   (bp slot tau is a pure function of S(tau)), so no workspace is needed.
//   Per-step issue drops ~350 -> ~160 cyc; live VGPRs ~210 -> ~110 (candA/B
//   shadow buffers and the 47-deep cndmask chain are gone).
// Phase 2 (parallel, 4096 one-wave blocks, 4 waves/SIMD): for each of the
//   1024*511 rows, re-derive cand = S[i] + trans[i][j], max3 tree, exact
//   first-occurrence eq-scan, overwrite the row with float(bp). Row is
//   read via wave-uniform s_load (192 B rows are 64 B aligned) before the
//   in-place store; each row touched by exactly one wave -> race-free.
//
// potentials: [1024, 512, 48] f32, transition: [48, 48] f32.
// out = backpointers [1024, 511, 48] (float-encoded) ++ scores [1024, 48].

constexpr int B_ = 1024;
constexpr int T_ = 512;
constexpr int K_ = 48;
constexpr int C_ = 6;                     // steps t=2..511 -> 510 = 6 * 85
constexpr int NROWS_ = B_ * (T_ - 1);     // 523264 bp/state rows

// ---------------------------------------------------------------------------
// Phase 1: Viterbi value recurrence. Writes S(t) into bp slot t (t=0..510)
// and final scores. No argmax anywhere.
// ---------------------------------------------------------------------------
__global__ __launch_bounds__(64, 1) void crf_phase1(
    const float* __restrict__ pot,
    const float* __restrict__ trans,
    float* __restrict__ out)
{
    const int b = blockIdx.x;
    const int j = threadIdx.x;  // 0..47 = destination tag

    __shared__ __align__(16) float stv[K_];

    // Transition column j -> 48 VGPRs (reused 511 times).
    float tcol[K_];
    #pragma unroll
    for (int i = 0; i < K_; ++i) tcol[i] = trans[i * K_ + j];

    const float* pp = pot + (size_t)b * T_ * K_ + j;
    float* srow     = out + (size_t)b * (T_ - 1) * K_ + j;  // walking S-slot ptr
    float* scout    = out + (size_t)B_ * (T_ - 1) * K_ + (size_t)b * K_ + j;

    // t = 0 state.
    float myst = pp[0];
    stv[j] = myst;
    *srow = myst;              // S(0) -> slot 0
    srow += K_;
    __builtin_amdgcn_wave_barrier();

// One recurrence step. cand is fully transient (no shadow, no double-buffer).
// DOST: store S(t) to slot t (true for t=1..510, false for t=511).
#define STEP1(PCUR, DOST)                                                     \
    do {                                                                      \
        /* Batched broadcast reads — 12 x ds_read_b128, static offsets. */    \
        float4 sv[12];                                                        \
        const float4* stv4 = (const float4*)stv;                              \
        _Pragma("unroll")                                                     \
        for (int c = 0; c < 12; ++c) sv[c] = stv4[c];                         \
        float cand[K_];                                                       \
        _Pragma("unroll")                                                     \
        for (int c = 0; c < 12; ++c) {                                        \
            cand[4 * c + 0] = sv[c].x + tcol[4 * c + 0];                      \
            cand[4 * c + 1] = sv[c].y + tcol[4 * c + 1];                      \
            cand[4 * c + 2] = sv[c].z + tcol[4 * c + 2];                      \
            cand[4 * c + 3] = sv[c].w + tcol[4 * c + 3];                      \
        }                                                                     \
        /* Ternary value tree -> v_max3_f32: 16+5+2+1 = 24 ops, depth 4. */   \
        float m1[16];                                                         \
        _Pragma("unroll")                                                     \
        for (int k = 0; k < 16; ++k)                                          \
            m1[k] = fmaxf(fmaxf(cand[3 * k], cand[3 * k + 1]), cand[3 * k + 2]); \
        float m2[6];                                                          \
        _Pragma("unroll")                                                     \
        for (int k = 0; k < 5; ++k)                                           \
            m2[k] = fmaxf(fmaxf(m1[3 * k], m1[3 * k + 1]), m1[3 * k + 2]);    \
        m2[5] = m1[15];                                                       \
        float mm = fmaxf(fmaxf(fmaxf(m2[0], m2[1]), m2[2]),                   \
                         fmaxf(fmaxf(m2[3], m2[4]), m2[5]));                  \
        myst = (PCUR) + mm;                                                   \
        if (DOST) *srow = myst;   /* S(t) -> slot t, fire-and-forget */       \
        srow += K_;                                                           \
        stv[j] = myst;                                                        \
        __builtin_amdgcn_wave_barrier();                                      \
    } while (0)

    // Potential for t=1 and prefetch t=2..7.
    float p1 = pp[(size_t)1 * K_];
    float pbuf[C_];
    #pragma unroll
    for (int u = 0; u < C_; ++u) pbuf[u] = pp[(size_t)(2 + u) * K_];

    STEP1(p1, true);   // t = 1 -> slot 1

    for (int t0 = 2; t0 < T_; t0 += C_) {   // t0 = 2, 8, ..., 506 (85 chunks)
        float pc[C_];
        #pragma unroll
        for (int u = 0; u < C_; ++u) pc[u] = pbuf[u];

        // Prefetch next chunk (clamped; dup loads harmless).
        #pragma unroll
        for (int u = 0; u < C_; ++u) {
            int tn = t0 + C_ + u;
            if (tn > T_ - 1) tn = T_ - 1;
            pbuf[u] = pp[(size_t)tn * K_];
        }

        STEP1(pc[0], true);
        STEP1(pc[1], true);
        STEP1(pc[2], true);
        STEP1(pc[3], true);
        STEP1(pc[4], true);
        STEP1(pc[5], t0 < T_ - C_);   // t = t0+5: store unless t == 511
    }

    // Final Viterbi scores (S(511)).
    *scout = myst;
#undef STEP1
}

// ---------------------------------------------------------------------------
// Phase 2: parallel argmax. Each wave owns rows (grid-stride); row holds
// S(tau); overwrite with float(argmax backpointers). 4096 waves -> 4/SIMD.
// ---------------------------------------------------------------------------
__global__ __launch_bounds__(64, 4) void crf_phase2(
    const float* __restrict__ trans,
    float* __restrict__ out)
{
    const int j = threadIdx.x;  // 0..47 = destination tag

    // Transition column j, loaded once per block (amortized over ~128 rows).
    float tcol[K_];
    #pragma unroll
    for (int i = 0; i < K_; ++i) tcol[i] = trans[i * K_ + j];

    for (int row = blockIdx.x; row < NROWS_; row += gridDim.x) {
        // Wave-uniform row pointer -> scalar loads (3x s_load_dwordx16;
        // rows are 192 B apart = 64 B aligned). Read BEFORE in-place store.
        const float* srow = out + (size_t)row * K_;
        float s[K_];
        #pragma unroll
        for (int i = 0; i < K_; ++i) s[i] = srow[i];

        float cand[K_];
        #pragma unroll
        for (int i = 0; i < K_; ++i) cand[i] = s[i] + tcol[i];

        // Exact max via max3 tree (identical arithmetic to phase-1/reference).
        float m1[16];
        #pragma unroll
        for (int k = 0; k < 16; ++k)
            m1[k] = fmaxf(fmaxf(cand[3 * k], cand[3 * k + 1]), cand[3 * k + 2]);
        float m2[6];
        #pragma unroll
        for (int k = 0; k < 5; ++k)
            m2[k] = fmaxf(fmaxf(m1[3 * k], m1[3 * k + 1]), m1[3 * k + 2]);
        m2[5] = m1[15];
        float mm = fmaxf(fmaxf(fmaxf(m2[0], m2[1]), m2[2]),
                         fmaxf(fmaxf(m2[3], m2[4]), m2[5]));

        // First-occurrence argmax (backward eq-scan keeps smallest i).
        int xx = K_ - 1;
        #pragma unroll
        for (int i = K_ - 2; i >= 0; --i)
            xx = (cand[i] == mm) ? i : xx;

        out[(size_t)row * K_ + j] = (float)xx;   // in-place overwrite
    }
}

extern "C" void kernel_launch(void* const* d_in, const int* in_sizes, int n_in,
                              void* d_out, int out_size, void* d_ws, size_t ws_size,
                              hipStream_t stream) {
    const float* pot   = (const float*)d_in[0];
    const float* trans = (const float*)d_in[1];
    float* out         = (float*)d_out;
    crf_phase1<<<dim3(B_), dim3(K_), 0, stream>>>(pot, trans, out);
    crf_phase2<<<dim3(4096), dim3(K_), 0, stream>>>(trans, out);
}

// Round 2
// 313.749 us; speedup vs baseline: 1.5780x; 1.5780x over previous
//
#include <hip/hip_runtime.h>

// CRF Viterbi forward decode — R6: fused R4 structure + store-hazard fix.
// potentials: [1024, 512, 48] f32, transition: [48, 48] f32.
// out = backpointers [1024, 511, 48] (as float values) ++ scores [1024, 48] f32.
//
// Block = 1 wave, 48 lanes, lane j = destination tag; 1 block per batch.
// Per step t: 12 ds_read_b128 broadcast -> shadow = step t-1's argmax
// (first-occurrence eq-scan vs exact max, numpy-identical) + bp store ->
// 48 adds -> max3 value tree -> myst -> ds_write -> wave_barrier.
//
// R5 post-mortem: split phases regressed (495 us). Phase2's launch_bounds
// starved registers (VGPR=64 -> trans reloaded per row). Phase1 alone was
// still 1066 cyc/step vs ~350 modeled: the per-step global store's DATA
// REGISTER is redefined on the next step, forcing a ~600 cyc s_waitcnt
// vmcnt store-ack stall per step if the allocator reuses the phys reg.
// R6 fix: rotating bpf0..bpf5 store-data registers (one per chunk slot),
// redefined only 6 steps (~2000 cyc) later; asm keep-alive defeats DSE so
// the allocator must keep 6 distinct regs. Everything else is R4.

constexpr int B_ = 1024;
constexpr int T_ = 512;
constexpr int K_ = 48;
constexpr int C_ = 6;   // steps t=2..511 -> 510 = 6 * 85, no remainder

__global__ __launch_bounds__(64, 1) void crf_viterbi_kernel(
    const float* __restrict__ pot,
    const float* __restrict__ trans,
    float* __restrict__ out)
{
    const int b = blockIdx.x;
    const int j = threadIdx.x;  // 0..47 = destination tag

    __shared__ __align__(16) float stv[K_];  // single wave-synchronous state buffer

    // Transition column j -> 48 VGPRs (reused 511 times).
    float tcol[K_];
    #pragma unroll
    for (int i = 0; i < K_; ++i) tcol[i] = trans[i * K_ + j];

    const float* pp = pot + (size_t)b * T_ * K_ + j;
    float* bpp      = out + (size_t)b * (T_ - 1) * K_ + j;          // walking bp ptr
    float* scout    = out + (size_t)B_ * (T_ - 1) * K_ + (size_t)b * K_ + j;

    // t = 0 state.
    float myst = pp[0];
    stv[j] = myst;
    __builtin_amdgcn_wave_barrier();

    // Parity-double-buffered candidates + exact max (shadow reads the buffer
    // the PREVIOUS step wrote; no register copies).
    float candA[K_], candB[K_];
    float mmA = 0.0f, mmB = 0.0f;

    // Rotating store-data registers: slot u is stored at chunk-step u and
    // only redefined one chunk (6 steps) later -> store-ack latency is
    // fully amortized, no per-step vmcnt stall.
    float bpf0 = 0.0f, bpf1 = 0.0f, bpf2 = 0.0f,
          bpf3 = 0.0f, bpf4 = 0.0f, bpf5 = 0.0f;

// One step. CN/MMN: written this step; CO/MMO: previous step's (shadow input).
// BPV: this step's dedicated store-data register. DOSH is a literal.
#define STEP(PCUR, CN, CO, MMN, MMO, DOSH, BPV)                                \
    do {                                                                       \
        /* (1) Batched broadcast reads — 12 x ds_read_b128, static offsets. */ \
        float4 sv[12];                                                         \
        const float4* stv4 = (const float4*)stv;                               \
        _Pragma("unroll")                                                      \
        for (int c = 0; c < 12; ++c) sv[c] = stv4[c];                          \
        /* (2) Shadow: previous step's argmax + bp store (fills LDS window) */ \
        if (DOSH) {                                                            \
            int xx = K_ - 1;                                                   \
            _Pragma("unroll")                                                  \
            for (int i = K_ - 2; i >= 0; --i)                                  \
                xx = (CO[i] == MMO) ? i : xx;   /* first-occurrence */         \
            BPV = (float)xx;                                                   \
            *bpp = BPV;                                                        \
            bpp += K_;                                                         \
        }                                                                      \
        /* (3) 48 candidates into the fresh buffer (old one now dead). */      \
        _Pragma("unroll")                                                      \
        for (int c = 0; c < 12; ++c) {                                         \
            CN[4 * c + 0] = sv[c].x + tcol[4 * c + 0];                         \
            CN[4 * c + 1] = sv[c].y + tcol[4 * c + 1];                         \
            CN[4 * c + 2] = sv[c].z + tcol[4 * c + 2];                         \
            CN[4 * c + 3] = sv[c].w + tcol[4 * c + 3];                         \
        }                                                                      \
        /* (4) Ternary value tree -> v_max3_f32: 16+5+2+1 = 24 ops, depth 4.*/ \
        float m1[16];                                                          \
        _Pragma("unroll")                                                      \
        for (int k = 0; k < 16; ++k)                                           \
            m1[k] = fmaxf(fmaxf(CN[3 * k], CN[3 * k + 1]), CN[3 * k + 2]);     \
        float m2[6];                                                           \
        _Pragma("unroll")                                                      \
        for (int k = 0; k < 5; ++k)                                            \
            m2[k] = fmaxf(fmaxf(m1[3 * k], m1[3 * k + 1]), m1[3 * k + 2]);     \
        m2[5] = m1[15];                                                        \
        float m30 = fmaxf(fmaxf(m2[0], m2[1]), m2[2]);                         \
        float m31 = fmaxf(fmaxf(m2[3], m2[4]), m2[5]);                         \
        float mm  = fmaxf(m30, m31);                                           \
        MMN = mm;                                                              \
        /* (5) New state -> LDS; fence orders write(t) before reads(t+1). */   \
        myst = (PCUR) + mm;                                                    \
        stv[j] = myst;                                                         \
        __builtin_amdgcn_wave_barrier();                                       \
    } while (0)

    // Potential for t=1 and prefetch t=2..7.
    float p1 = pp[(size_t)1 * K_];
    float pbuf[C_];
    #pragma unroll
    for (int u = 0; u < C_; ++u) pbuf[u] = pp[(size_t)(2 + u) * K_];

    // t = 1 (odd): writes candB; no shadow yet (BPV arg unused).
    STEP(p1, candB, candA, mmB, mmA, false, bpf0);

    for (int t0 = 2; t0 < T_; t0 += C_) {   // t0 = 2, 8, ..., 506 (85 chunks)
        float pc[C_];
        #pragma unroll
        for (int u = 0; u < C_; ++u) pc[u] = pbuf[u];

        // Prefetch next chunk (clamped; dup loads harmless; 6-step slack).
        #pragma unroll
        for (int u = 0; u < C_; ++u) {
            int tn = t0 + C_ + u;
            if (tn > T_ - 1) tn = T_ - 1;
            pbuf[u] = pp[(size_t)tn * K_];
        }

        // t = t0 + u; even t writes A / reads B, odd t writes B / reads A.
        STEP(pc[0], candA, candB, mmA, mmB, true, bpf0);
        STEP(pc[1], candB, candA, mmB, mmA, true, bpf1);
        STEP(pc[2], candA, candB, mmA, mmB, true, bpf2);
        STEP(pc[3], candB, candA, mmB, mmA, true, bpf3);
        STEP(pc[4], candA, candB, mmA, mmB, true, bpf4);
        STEP(pc[5], candB, candA, mmB, mmA, true, bpf5);
    }

    // Final shadow: argmax for t = 511 (odd -> candB/mmB).
    {
        int xx = K_ - 1;
        #pragma unroll
        for (int i = K_ - 2; i >= 0; --i)
            xx = (candB[i] == mmB) ? i : xx;
        *bpp = (float)xx;
    }

    // Keep the rotating store registers live to the end of the kernel so the
    // in-step array-slot writes are not dead-store-eliminated (which would
    // collapse the rotation back to a single immediately-reused register).
    asm volatile("" :: "v"(bpf0), "v"(bpf1), "v"(bpf2),
                       "v"(bpf3), "v"(bpf4), "v"(bpf5));

    // Final Viterbi scores.
    *scout = myst;
#undef STEP
}

extern "C" void kernel_launch(void* const* d_in, const int* in_sizes, int n_in,
                              void* d_out, int out_size, void* d_ws, size_t ws_size,
                              hipStream_t stream) {
    const float* pot   = (const float*)d_in[0];
    const float* trans = (const float*)d_in[1];
    float* out         = (float*)d_out;
    crf_viterbi_kernel<<<dim3(B_), dim3(K_), 0, stream>>>(pot, trans, out);
}